// Round 5
// baseline (863.205 us; speedup 1.0000x reference)
//
#include <hip/hip_runtime.h>
#include <stdint.h>

#define N_NODES 100000
#define N_EDGES 1600000
#define FDIM 128
#define NH 8
#define NCLS 3

static constexpr float SCALE = 0.25f; // D^-0.5, D=16

// ---------------- histogram of dst ----------------
__global__ __launch_bounds__(256) void k_hist(const int* __restrict__ ei,
                                              int* __restrict__ cnt) {
    int e = blockIdx.x * 256 + threadIdx.x;
    if (e < N_EDGES) {
        int d = ei[N_EDGES + e];
        atomicAdd(&cnt[d], 1);
    }
}

// ---------------- scan step 1: block sums (1024 elems/block) ----------------
__global__ __launch_bounds__(256) void k_scan1(const int* __restrict__ cnt,
                                               int* __restrict__ bsum) {
    __shared__ int sd[256];
    int t = threadIdx.x;
    int i0 = blockIdx.x * 1024 + t * 4;
    int s = 0;
#pragma unroll
    for (int j = 0; j < 4; ++j) {
        int i = i0 + j;
        if (i < N_NODES) s += cnt[i];
    }
    sd[t] = s;
    __syncthreads();
    for (int off = 128; off > 0; off >>= 1) {
        if (t < off) sd[t] += sd[t + off];
        __syncthreads();
    }
    if (t == 0) bsum[blockIdx.x] = sd[0];
}

// ---------------- scan step 2: scan of 98 block sums ----------------
__global__ __launch_bounds__(128) void k_scan2(const int* __restrict__ bsum,
                                               int* __restrict__ boff,
                                               int* __restrict__ row_start) {
    __shared__ int sd[128];
    int t = threadIdx.x;
    int v = (t < 98) ? bsum[t] : 0;
    sd[t] = v;
    __syncthreads();
    for (int off = 1; off < 128; off <<= 1) {
        int add = (t >= off) ? sd[t - off] : 0;
        __syncthreads();
        sd[t] += add;
        __syncthreads();
    }
    if (t < 98) boff[t] = sd[t] - v; // exclusive
    if (t == 0) row_start[N_NODES] = N_EDGES;
}

// ---------------- scan step 3: full exclusive scan -> row_start, cursor ----------------
__global__ __launch_bounds__(256) void k_scan3(const int* __restrict__ cnt,
                                               const int* __restrict__ boff,
                                               int* __restrict__ row_start,
                                               int* __restrict__ cursor) {
    __shared__ int sd[256];
    int t = threadIdx.x;
    int i0 = blockIdx.x * 1024 + t * 4;
    int c[4];
    int s = 0;
#pragma unroll
    for (int j = 0; j < 4; ++j) {
        int i = i0 + j;
        c[j] = (i < N_NODES) ? cnt[i] : 0;
        s += c[j];
    }
    sd[t] = s;
    __syncthreads();
    for (int off = 1; off < 256; off <<= 1) {
        int add = (t >= off) ? sd[t - off] : 0;
        __syncthreads();
        sd[t] += add;
        __syncthreads();
    }
    int run = boff[blockIdx.x] + sd[t] - s;
#pragma unroll
    for (int j = 0; j < 4; ++j) {
        int i = i0 + j;
        if (i < N_NODES) { row_start[i] = run; cursor[i] = run; }
        run += c[j];
    }
}

// ---------------- scatter edges into CSR order, folding edge_attr into record ----------------
// se4 = { src_as_float_bits, ea0, ea1, unused }
__global__ __launch_bounds__(256) void k_scatter(const int* __restrict__ ei,
                                                 const float* __restrict__ ea,
                                                 int* __restrict__ cursor,
                                                 float4* __restrict__ se4) {
    int e = blockIdx.x * 256 + threadIdx.x;
    if (e < N_EDGES) {
        int s = ei[e];
        int d = ei[N_EDGES + e];
        float2 a = *(const float2*)(ea + (long)e * 2);
        int pos = atomicAdd(&cursor[d], 1);
        se4[pos] = make_float4(__int_as_float(s), a.x, a.y, 0.0f);
    }
}

// ---------------- tiled fp32 GEMM: C[N x COLS] = A[N x 128] @ W[128 x COLS] ----------------
// SPLIT: route cols 0-127 -> Cq (stride 128), cols 128-383 -> Ckv (stride 256)
// RESID: C += bias + resid
template <int COLS, bool RESID, bool SPLIT>
__global__ __launch_bounds__(256) void k_gemm(const float* __restrict__ A,
                                              const float* __restrict__ W,
                                              const float* __restrict__ bias,
                                              const float* __restrict__ resid,
                                              float* __restrict__ Cq,
                                              float* __restrict__ Ckv) {
    __shared__ float xT[128 * 68]; // [k][row], padded stride 68
    int rb = blockIdx.x * 64;
    int cb = blockIdx.y * 64;
    int t = threadIdx.x;
    int tx = t & 15, ty = t >> 4;

    // stage A rows rb..rb+63 transposed into LDS
#pragma unroll
    for (int it = 0; it < 8; ++it) {
        int f = (it * 256 + t) * 4;
        int r = f >> 7;
        int kk = f & 127;
        int row = rb + r;
        float4 v = make_float4(0.f, 0.f, 0.f, 0.f);
        if (row < N_NODES) v = *(const float4*)(A + (long)row * 128 + kk);
        xT[(kk + 0) * 68 + r] = v.x;
        xT[(kk + 1) * 68 + r] = v.y;
        xT[(kk + 2) * 68 + r] = v.z;
        xT[(kk + 3) * 68 + r] = v.w;
    }
    __syncthreads();

    float acc[4][4] = {};
    const float* Wp = W + cb + tx * 4;
#pragma unroll 8
    for (int k = 0; k < 128; ++k) {
        float4 xv = *(const float4*)(xT + k * 68 + ty * 4);
        float4 wv = *(const float4*)(Wp + (long)k * COLS);
        acc[0][0] += xv.x * wv.x; acc[0][1] += xv.x * wv.y; acc[0][2] += xv.x * wv.z; acc[0][3] += xv.x * wv.w;
        acc[1][0] += xv.y * wv.x; acc[1][1] += xv.y * wv.y; acc[1][2] += xv.y * wv.z; acc[1][3] += xv.y * wv.w;
        acc[2][0] += xv.z * wv.x; acc[2][1] += xv.z * wv.y; acc[2][2] += xv.z * wv.z; acc[2][3] += xv.z * wv.w;
        acc[3][0] += xv.w * wv.x; acc[3][1] += xv.w * wv.y; acc[3][2] += xv.w * wv.z; acc[3][3] += xv.w * wv.w;
    }

    float4 bv = make_float4(0.f, 0.f, 0.f, 0.f);
    if (RESID) bv = *(const float4*)(bias + cb + tx * 4);

    // output base per destination table
    float* Cbase;
    long  stride;
    int   ccol;
    if (SPLIT) {
        if (cb < 128) { Cbase = Cq;  stride = 128; ccol = cb; }
        else          { Cbase = Ckv; stride = 256; ccol = cb - 128; }
    } else {
        Cbase = Cq; stride = COLS; ccol = cb;
    }

#pragma unroll
    for (int i = 0; i < 4; ++i) {
        int row = rb + ty * 4 + i;
        if (row < N_NODES) {
            float4 o = make_float4(acc[i][0], acc[i][1], acc[i][2], acc[i][3]);
            if (RESID) {
                float4 rv = *(const float4*)(resid + (long)row * 128 + cb + tx * 4);
                o.x += rv.x + bv.x; o.y += rv.y + bv.y;
                o.z += rv.z + bv.z; o.w += rv.w + bv.w;
            }
            *(float4*)(Cbase + (long)row * stride + ccol + tx * 4) = o;
        }
    }
}

// ---------------- per-node edge attention ----------------
// one wave per node; 4 groups of 16 lanes, each group owns one edge per iteration;
// each lane covers 8 feature dims (32B k + 32B v loads).
__global__ __launch_bounds__(256) void k_attn(const float* __restrict__ q_tab,
                                              const float* __restrict__ kv_tab,
                                              const float4* __restrict__ se4,
                                              const int* __restrict__ row_start,
                                              const float* __restrict__ Wedge,
                                              float* __restrict__ agg) {
    int wave = threadIdx.x >> 6;
    int lane = threadIdx.x & 63;
    int node = blockIdx.x * 4 + wave;
    if (node >= N_NODES) return;

    int g  = lane >> 4;      // edge group 0..3
    int gl = lane & 15;      // lane within group: dims gl*8 .. gl*8+7
    int h  = gl >> 1;        // head of these 8 dims

    int p0 = row_start[node], p1 = row_start[node + 1];
    if (p0 == p1) { // degree-0: reference yields zeros
        if (g == 0) {
            *(float4*)(agg + (long)node * 128 + gl * 8)     = make_float4(0.f, 0.f, 0.f, 0.f);
            *(float4*)(agg + (long)node * 128 + gl * 8 + 4) = make_float4(0.f, 0.f, 0.f, 0.f);
        }
        return;
    }

    float we0 = Wedge[h];
    float we1 = Wedge[8 + h];
    const float* qb = q_tab + (long)node * 128 + gl * 8;
    float4 qa = *(const float4*)(qb);
    float4 qbv = *(const float4*)(qb + 4);

    float4 acc0 = make_float4(0.f, 0.f, 0.f, 0.f);
    float4 acc1 = make_float4(0.f, 0.f, 0.f, 0.f);
    float den = 0.f;

    int last = p1 - 1;
    float4 rec = se4[min(p0 + g, last)];
    for (int p = p0; p < p1; p += 4) {
        float4 cur = rec;
        int pn = p + 4;
        if (pn < p1) rec = se4[min(pn + g, last)]; // prefetch next records (uniform branch)

        bool valid = (p + g) < p1;
        int src = __float_as_int(cur.x);
        const float* kvb = kv_tab + (long)src * 256 + gl * 8;
        float4 ka = *(const float4*)(kvb);
        float4 kb = *(const float4*)(kvb + 4);
        float4 va = *(const float4*)(kvb + 128);
        float4 vb = *(const float4*)(kvb + 132);

        float part = qa.x * ka.x + qa.y * ka.y + qa.z * ka.z + qa.w * ka.w
                   + qbv.x * kb.x + qbv.y * kb.y + qbv.z * kb.z + qbv.w * kb.w;
        part += __shfl_xor(part, 1); // head-dot complete in both lanes of the pair

        float s = part * SCALE + cur.y * we0 + cur.z * we1;
        float w = valid ? __expf(s) : 0.f;
        den += w;
        acc0.x += w * va.x; acc0.y += w * va.y; acc0.z += w * va.z; acc0.w += w * va.w;
        acc1.x += w * vb.x; acc1.y += w * vb.y; acc1.z += w * vb.z; acc1.w += w * vb.w;
    }

    // combine the 4 edge-groups (each lane quad holds same dims)
#pragma unroll
    for (int off = 16; off <= 32; off <<= 1) {
        acc0.x += __shfl_xor(acc0.x, off); acc0.y += __shfl_xor(acc0.y, off);
        acc0.z += __shfl_xor(acc0.z, off); acc0.w += __shfl_xor(acc0.w, off);
        acc1.x += __shfl_xor(acc1.x, off); acc1.y += __shfl_xor(acc1.y, off);
        acc1.z += __shfl_xor(acc1.z, off); acc1.w += __shfl_xor(acc1.w, off);
        den += __shfl_xor(den, off);
    }

    if (g == 0) {
        float inv = 1.0f / (den + 1e-16f);
        float* ob = agg + (long)node * 128 + gl * 8;
        *(float4*)(ob)     = make_float4(acc0.x * inv, acc0.y * inv, acc0.z * inv, acc0.w * inv);
        *(float4*)(ob + 4) = make_float4(acc1.x * inv, acc1.y * inv, acc1.z * inv, acc1.w * inv);
    }
}

// ---------------- LN + MLP (fused), 4 nodes per wave ----------------
__global__ __launch_bounds__(256) void k_mlp(const float* __restrict__ h_pre,
                                             const float* __restrict__ ln_w,
                                             const float* __restrict__ ln_b,
                                             const float* __restrict__ Wc1,
                                             const float* __restrict__ bc1,
                                             const float* __restrict__ Wc2,
                                             const float* __restrict__ bc2,
                                             float* __restrict__ out) {
    __shared__ float sW1[128 * 64];
    __shared__ float sW2[64 * 3];
    __shared__ float sb1[64];
    __shared__ float sb2[3];
    __shared__ float hbuf[4][4][128];
    int t = threadIdx.x;
#pragma unroll
    for (int it = 0; it < 8; ++it) {
        int f = (it * 256 + t) * 4;
        *(float4*)(sW1 + f) = *(const float4*)(Wc1 + f);
    }
    if (t < 192) sW2[t] = Wc2[t];
    if (t < 64) sb1[t] = bc1[t];
    if (t < 3) sb2[t] = bc2[t];
    __syncthreads();

    int wave = t >> 6, lane = t & 63;
    float2 lw = *(const float2*)(ln_w + lane * 2);
    float2 lb = *(const float2*)(ln_b + lane * 2);
    int nb0 = (blockIdx.x * 4 + wave) * 4;

#pragma unroll
    for (int nb = 0; nb < 4; ++nb) {
        int node = nb0 + nb;
        float2 hv = *(const float2*)(h_pre + (long)node * 128 + lane * 2);
        float s = hv.x + hv.y;
#pragma unroll
        for (int off = 32; off > 0; off >>= 1) s += __shfl_xor(s, off);
        float mu = s * (1.0f / 128.0f);
        float dx = hv.x - mu, dy = hv.y - mu;
        float s2 = dx * dx + dy * dy;
#pragma unroll
        for (int off = 32; off > 0; off >>= 1) s2 += __shfl_xor(s2, off);
        float rstd = rsqrtf(s2 * (1.0f / 128.0f) + 1e-5f);
        hbuf[wave][nb][lane * 2] = dx * rstd * lw.x + lb.x;
        hbuf[wave][nb][lane * 2 + 1] = dy * rstd * lw.y + lb.y;
    }
    __syncthreads();

    float acc[4];
#pragma unroll
    for (int nb = 0; nb < 4; ++nb) acc[nb] = sb1[lane];
#pragma unroll 4
    for (int c = 0; c < 128; ++c) {
        float w = sW1[c * 64 + lane];
        acc[0] += hbuf[wave][0][c] * w;
        acc[1] += hbuf[wave][1][c] * w;
        acc[2] += hbuf[wave][2][c] * w;
        acc[3] += hbuf[wave][3][c] * w;
    }
#pragma unroll
    for (int nb = 0; nb < 4; ++nb) {
        float a = fmaxf(acc[nb], 0.f);
#pragma unroll
        for (int c2 = 0; c2 < NCLS; ++c2) {
            float pv = a * sW2[lane * 3 + c2];
#pragma unroll
            for (int off = 32; off > 0; off >>= 1) pv += __shfl_xor(pv, off);
            if (lane == 0) out[(long)(nb0 + nb) * 3 + c2] = pv + sb2[c2];
        }
    }
}

extern "C" void kernel_launch(void* const* d_in, const int* in_sizes, int n_in,
                              void* d_out, int out_size, void* d_ws, size_t ws_size,
                              hipStream_t stream) {
    const float* x         = (const float*)d_in[0];
    const int*   edge_index= (const int*)d_in[1];   // harness stages integers as int32
    const float* edge_attr = (const float*)d_in[2];
    const float* Wqkv      = (const float*)d_in[3];
    const float* Wedge     = (const float*)d_in[4];
    const float* Wout      = (const float*)d_in[5];
    const float* bout      = (const float*)d_in[6];
    const float* ln_w      = (const float*)d_in[7];
    const float* ln_b      = (const float*)d_in[8];
    const float* Wc1       = (const float*)d_in[9];
    const float* bc1       = (const float*)d_in[10];
    const float* Wc2       = (const float*)d_in[11];
    const float* bc2       = (const float*)d_in[12];
    float* out = (float*)d_out;

    // workspace layout (~232 MB)
    char* ws = (char*)d_ws;
    size_t o = 0;
    auto alloc = [&](size_t bytes) -> char* {
        char* p = ws + o;
        o = (o + bytes + 255) & ~(size_t)255;
        return p;
    };
    int*    cnt       = (int*)alloc((size_t)N_NODES * 4);
    int*    row_start = (int*)alloc((size_t)(N_NODES + 1) * 4);
    int*    cursor    = (int*)alloc((size_t)N_NODES * 4);
    int*    bsum      = (int*)alloc(98 * 4);
    int*    boff      = (int*)alloc(98 * 4);
    float4* se4       = (float4*)alloc((size_t)N_EDGES * 16);
    float*  agg       = (float*)alloc((size_t)N_NODES * 128 * 4);
    float*  q_tab     = (float*)alloc((size_t)N_NODES * 128 * 4);
    float*  kv_tab    = (float*)alloc((size_t)N_NODES * 256 * 4);
    float*  h_pre     = q_tab; // alias: q dead once k_attn completes
    (void)ws_size; (void)in_sizes; (void)n_in; (void)out_size;

    hipMemsetAsync(cnt, 0, (size_t)N_NODES * 4, stream);
    k_hist<<<N_EDGES / 256, 256, 0, stream>>>(edge_index, cnt);
    k_scan1<<<98, 256, 0, stream>>>(cnt, bsum);
    k_scan2<<<1, 128, 0, stream>>>(bsum, boff, row_start);
    k_scan3<<<98, 256, 0, stream>>>(cnt, boff, row_start, cursor);
    k_scatter<<<N_EDGES / 256, 256, 0, stream>>>(edge_index, edge_attr, cursor, se4);

    k_gemm<384, false, true><<<dim3(1563, 6), 256, 0, stream>>>(x, Wqkv, nullptr, nullptr, q_tab, kv_tab);
    k_attn<<<25000, 256, 0, stream>>>(q_tab, kv_tab, se4, row_start, Wedge, agg);
    k_gemm<128, true, false><<<dim3(1563, 2), 256, 0, stream>>>(agg, Wout, bout, x, h_pre, nullptr);
    k_mlp<<<6250, 256, 0, stream>>>(h_pre, ln_w, ln_b, Wc1, bc1, Wc2, bc2, out);
}

// Round 7
// 637.869 us; speedup vs baseline: 1.3533x; 1.3533x over previous
//
#include <hip/hip_runtime.h>
#include <stdint.h>

#define N_NODES 100000
#define N_EDGES 1600000
#define FDIM 128
#define NH 8
#define NCLS 3

static constexpr float SCALE = 0.25f; // D^-0.5, D=16

typedef _Float16 f16x8 __attribute__((ext_vector_type(8)));
typedef _Float16 f16x4 __attribute__((ext_vector_type(4)));
typedef float    f32x4 __attribute__((ext_vector_type(4)));

// ---------------- histogram of dst ----------------
__global__ __launch_bounds__(256) void k_hist(const int* __restrict__ ei,
                                              int* __restrict__ cnt) {
    int e = blockIdx.x * 256 + threadIdx.x;
    if (e < N_EDGES) {
        int d = ei[N_EDGES + e];
        atomicAdd(&cnt[d], 1);
    }
}

// ---------------- scan step 1 ----------------
__global__ __launch_bounds__(256) void k_scan1(const int* __restrict__ cnt,
                                               int* __restrict__ bsum) {
    __shared__ int sd[256];
    int t = threadIdx.x;
    int i0 = blockIdx.x * 1024 + t * 4;
    int s = 0;
#pragma unroll
    for (int j = 0; j < 4; ++j) {
        int i = i0 + j;
        if (i < N_NODES) s += cnt[i];
    }
    sd[t] = s;
    __syncthreads();
    for (int off = 128; off > 0; off >>= 1) {
        if (t < off) sd[t] += sd[t + off];
        __syncthreads();
    }
    if (t == 0) bsum[blockIdx.x] = sd[0];
}

// ---------------- scan step 2 ----------------
__global__ __launch_bounds__(128) void k_scan2(const int* __restrict__ bsum,
                                               int* __restrict__ boff,
                                               int* __restrict__ row_start) {
    __shared__ int sd[128];
    int t = threadIdx.x;
    int v = (t < 98) ? bsum[t] : 0;
    sd[t] = v;
    __syncthreads();
    for (int off = 1; off < 128; off <<= 1) {
        int add = (t >= off) ? sd[t - off] : 0;
        __syncthreads();
        sd[t] += add;
        __syncthreads();
    }
    if (t < 98) boff[t] = sd[t] - v; // exclusive
    if (t == 0) row_start[N_NODES] = N_EDGES;
}

// ---------------- scan step 3 ----------------
__global__ __launch_bounds__(256) void k_scan3(const int* __restrict__ cnt,
                                               const int* __restrict__ boff,
                                               int* __restrict__ row_start,
                                               int* __restrict__ cursor) {
    __shared__ int sd[256];
    int t = threadIdx.x;
    int i0 = blockIdx.x * 1024 + t * 4;
    int c[4];
    int s = 0;
#pragma unroll
    for (int j = 0; j < 4; ++j) {
        int i = i0 + j;
        c[j] = (i < N_NODES) ? cnt[i] : 0;
        s += c[j];
    }
    sd[t] = s;
    __syncthreads();
    for (int off = 1; off < 256; off <<= 1) {
        int add = (t >= off) ? sd[t - off] : 0;
        __syncthreads();
        sd[t] += add;
        __syncthreads();
    }
    int run = boff[blockIdx.x] + sd[t] - s;
#pragma unroll
    for (int j = 0; j < 4; ++j) {
        int i = i0 + j;
        if (i < N_NODES) { row_start[i] = run; cursor[i] = run; }
        run += c[j];
    }
}

// ---------------- scatter edges into CSR order (edge_attr folded in) ----------------
__global__ __launch_bounds__(256) void k_scatter(const int* __restrict__ ei,
                                                 const float* __restrict__ ea,
                                                 int* __restrict__ cursor,
                                                 float4* __restrict__ se4) {
    int e = blockIdx.x * 256 + threadIdx.x;
    if (e < N_EDGES) {
        int s = ei[e];
        int d = ei[N_EDGES + e];
        float2 a = *(const float2*)(ea + (long)e * 2);
        int pos = atomicAdd(&cursor[d], 1);
        se4[pos] = make_float4(__int_as_float(s), a.x, a.y, 0.0f);
    }
}

// ---------------- convert x -> fp16, W's -> fp16 transposed ----------------
__global__ __launch_bounds__(256) void k_cvt(const float* __restrict__ x,
                                             const float* __restrict__ Wqkv,
                                             const float* __restrict__ Wout,
                                             _Float16* __restrict__ x_h,
                                             _Float16* __restrict__ Wqkv_t,  // [384][128]
                                             _Float16* __restrict__ Wout_t) { // [128][128]
    long i = (long)blockIdx.x * 256 + threadIdx.x; // grid = 12500 blocks -> 3.2M exact
    float4 v = ((const float4*)x)[i];
    f16x4 h = { (_Float16)v.x, (_Float16)v.y, (_Float16)v.z, (_Float16)v.w };
    *(f16x4*)(x_h + i * 4) = h;
    if (i < 128 * 384) { // Wqkv[k][n] -> Wqkv_t[n][k]
        int k = (int)(i / 384), n = (int)(i % 384);
        Wqkv_t[(long)n * 128 + k] = (_Float16)Wqkv[i];
    }
    if (i < 128 * 128) {
        int k = (int)(i / 128), n = (int)(i % 128);
        Wout_t[(long)n * 128 + k] = (_Float16)Wout[i];
    }
}

// ---------------- MFMA qkv GEMM: [N x 128] @ [128 x 384] -> q (f32), kv (f16) ----------------
// 4 waves/block, 16 rows/wave, all 384 cols per wave (24 col-frags), K=128 in 4 steps.
__global__ __launch_bounds__(256) void k_mm_qkv(const _Float16* __restrict__ x_h,
                                                const _Float16* __restrict__ Wt, // [384][128]
                                                float* __restrict__ q_tab,
                                                _Float16* __restrict__ kv_h) {
    int wave = threadIdx.x >> 6, l = threadIdx.x & 63;
    int row0 = blockIdx.x * 64 + wave * 16;
    int lr = l & 15, lg = l >> 4;
    int arow = row0 + lr;
    bool aok = arow < N_NODES;
    long abase = (long)arow * 128 + lg * 8;

    f32x4 acc[24];
#pragma unroll
    for (int c = 0; c < 24; ++c) acc[c] = (f32x4){0.f, 0.f, 0.f, 0.f};

#pragma unroll
    for (int kk = 0; kk < 4; ++kk) {
        f16x8 a = aok ? *(const f16x8*)(x_h + abase + kk * 32) : (f16x8){};
        const _Float16* wb = Wt + (long)lr * 128 + lg * 8 + kk * 32;
#pragma unroll
        for (int c = 0; c < 24; ++c) {
            f16x8 b = *(const f16x8*)(wb + (long)c * 16 * 128);
            acc[c] = __builtin_amdgcn_mfma_f32_16x16x32_f16(a, b, acc[c], 0, 0, 0);
        }
    }

    int orow_base = row0 + lg * 4;
#pragma unroll
    for (int c = 0; c < 24; ++c) {
#pragma unroll
        for (int j = 0; j < 4; ++j) {
            int orow = orow_base + j;
            if (orow < N_NODES) {
                float v = acc[c][j];
                if (c < 8)       q_tab[(long)orow * 128 + c * 16 + lr] = v;
                else if (c < 16) kv_h[(long)orow * 256 + (c - 8) * 16 + lr]        = (_Float16)v;
                else             kv_h[(long)orow * 256 + 128 + (c - 16) * 16 + lr] = (_Float16)v;
            }
        }
    }
}

// ---------------- MFMA out GEMM: agg_h[N x 128] @ Wout_t -> h_pre = . + bout + x ----------------
__global__ __launch_bounds__(256) void k_mm_out(const _Float16* __restrict__ agg_h,
                                                const _Float16* __restrict__ Wot, // [128][128]
                                                const float* __restrict__ bout,
                                                const float* __restrict__ x,
                                                float* __restrict__ h_pre) {
    int wave = threadIdx.x >> 6, l = threadIdx.x & 63;
    int row0 = blockIdx.x * 64 + wave * 16;
    int lr = l & 15, lg = l >> 4;
    int arow = row0 + lr;
    bool aok = arow < N_NODES;
    long abase = (long)arow * 128 + lg * 8;

    f32x4 acc[8];
#pragma unroll
    for (int c = 0; c < 8; ++c) acc[c] = (f32x4){0.f, 0.f, 0.f, 0.f};

#pragma unroll
    for (int kk = 0; kk < 4; ++kk) {
        f16x8 a = aok ? *(const f16x8*)(agg_h + abase + kk * 32) : (f16x8){};
        const _Float16* wb = Wot + (long)lr * 128 + lg * 8 + kk * 32;
#pragma unroll
        for (int c = 0; c < 8; ++c) {
            f16x8 b = *(const f16x8*)(wb + (long)c * 16 * 128);
            acc[c] = __builtin_amdgcn_mfma_f32_16x16x32_f16(a, b, acc[c], 0, 0, 0);
        }
    }

    int orow_base = row0 + lg * 4;
#pragma unroll
    for (int c = 0; c < 8; ++c) {
        int ocol = c * 16 + lr;
        float bv = bout[ocol];
#pragma unroll
        for (int j = 0; j < 4; ++j) {
            int orow = orow_base + j;
            if (orow < N_NODES) {
                h_pre[(long)orow * 128 + ocol] = acc[c][j] + bv + x[(long)orow * 128 + ocol];
            }
        }
    }
}

// ---------------- per-node edge attention (fp16 kv, fp16 agg out) ----------------
// one wave per node; 4 groups x 16 lanes; each lane covers 8 dims (16B f16 loads).
__global__ __launch_bounds__(256) void k_attn(const float* __restrict__ q_tab,
                                              const _Float16* __restrict__ kv_tab,
                                              const float4* __restrict__ se4,
                                              const int* __restrict__ row_start,
                                              const float* __restrict__ Wedge,
                                              _Float16* __restrict__ agg_h) {
    int wave = threadIdx.x >> 6;
    int lane = threadIdx.x & 63;
    int node = blockIdx.x * 4 + wave;
    if (node >= N_NODES) return;

    int g  = lane >> 4;      // edge group 0..3
    int gl = lane & 15;      // dims gl*8 .. gl*8+7
    int h  = gl >> 1;        // head of these 8 dims

    int p0 = row_start[node], p1 = row_start[node + 1];
    if (p0 == p1) { // degree-0: zeros
        if (g == 0) *(f16x8*)(agg_h + (long)node * 128 + gl * 8) = (f16x8){};
        return;
    }

    float we0 = Wedge[h];
    float we1 = Wedge[8 + h];
    const float* qb = q_tab + (long)node * 128 + gl * 8;
    float4 qa  = *(const float4*)(qb);
    float4 qbv = *(const float4*)(qb + 4);

    float a0=0.f,a1=0.f,a2=0.f,a3=0.f,a4=0.f,a5=0.f,a6=0.f,a7=0.f;
    float den = 0.f;

    int last = p1 - 1;
    float4 rec = se4[min(p0 + g, last)];
    for (int p = p0; p < p1; p += 4) {
        float4 cur = rec;
        int pn = p + 4;
        if (pn < p1) rec = se4[min(pn + g, last)];

        bool valid = (p + g) < p1;
        int src = __float_as_int(cur.x);
        const _Float16* kvb = kv_tab + (long)src * 256 + gl * 8;
        f16x8 kh = *(const f16x8*)(kvb);
        f16x8 vh = *(const f16x8*)(kvb + 128);

        float part = qa.x  * (float)kh[0] + qa.y  * (float)kh[1]
                   + qa.z  * (float)kh[2] + qa.w  * (float)kh[3]
                   + qbv.x * (float)kh[4] + qbv.y * (float)kh[5]
                   + qbv.z * (float)kh[6] + qbv.w * (float)kh[7];
        part += __shfl_xor(part, 1); // complete 16-dim head dot within lane pair

        float s = part * SCALE + cur.y * we0 + cur.z * we1;
        float w = valid ? __expf(s) : 0.f;
        den += w;
        a0 += w * (float)vh[0]; a1 += w * (float)vh[1];
        a2 += w * (float)vh[2]; a3 += w * (float)vh[3];
        a4 += w * (float)vh[4]; a5 += w * (float)vh[5];
        a6 += w * (float)vh[6]; a7 += w * (float)vh[7];
    }

    // combine the 4 edge-groups
#pragma unroll
    for (int off = 16; off <= 32; off <<= 1) {
        a0 += __shfl_xor(a0, off); a1 += __shfl_xor(a1, off);
        a2 += __shfl_xor(a2, off); a3 += __shfl_xor(a3, off);
        a4 += __shfl_xor(a4, off); a5 += __shfl_xor(a5, off);
        a6 += __shfl_xor(a6, off); a7 += __shfl_xor(a7, off);
        den += __shfl_xor(den, off);
    }

    if (g == 0) {
        float inv = 1.0f / (den + 1e-16f);
        f16x8 o = { (_Float16)(a0 * inv), (_Float16)(a1 * inv),
                    (_Float16)(a2 * inv), (_Float16)(a3 * inv),
                    (_Float16)(a4 * inv), (_Float16)(a5 * inv),
                    (_Float16)(a6 * inv), (_Float16)(a7 * inv) };
        *(f16x8*)(agg_h + (long)node * 128 + gl * 8) = o;
    }
}

// ---------------- LN + MLP (fused), 4 nodes per wave ----------------
__global__ __launch_bounds__(256) void k_mlp(const float* __restrict__ h_pre,
                                             const float* __restrict__ ln_w,
                                             const float* __restrict__ ln_b,
                                             const float* __restrict__ Wc1,
                                             const float* __restrict__ bc1,
                                             const float* __restrict__ Wc2,
                                             const float* __restrict__ bc2,
                                             float* __restrict__ out) {
    __shared__ float sW1[128 * 64];
    __shared__ float sW2[64 * 3];
    __shared__ float sb1[64];
    __shared__ float sb2[3];
    __shared__ float hbuf[4][4][128];
    int t = threadIdx.x;
#pragma unroll
    for (int it = 0; it < 8; ++it) {
        int f = (it * 256 + t) * 4;
        *(float4*)(sW1 + f) = *(const float4*)(Wc1 + f);
    }
    if (t < 192) sW2[t] = Wc2[t];
    if (t < 64) sb1[t] = bc1[t];
    if (t < 3) sb2[t] = bc2[t];
    __syncthreads();

    int wave = t >> 6, lane = t & 63;
    float2 lw = *(const float2*)(ln_w + lane * 2);
    float2 lb = *(const float2*)(ln_b + lane * 2);
    int nb0 = (blockIdx.x * 4 + wave) * 4;

#pragma unroll
    for (int nb = 0; nb < 4; ++nb) {
        int node = nb0 + nb;
        float2 hv = *(const float2*)(h_pre + (long)node * 128 + lane * 2);
        float s = hv.x + hv.y;
#pragma unroll
        for (int off = 32; off > 0; off >>= 1) s += __shfl_xor(s, off);
        float mu = s * (1.0f / 128.0f);
        float dx = hv.x - mu, dy = hv.y - mu;
        float s2 = dx * dx + dy * dy;
#pragma unroll
        for (int off = 32; off > 0; off >>= 1) s2 += __shfl_xor(s2, off);
        float rstd = rsqrtf(s2 * (1.0f / 128.0f) + 1e-5f);
        hbuf[wave][nb][lane * 2] = dx * rstd * lw.x + lb.x;
        hbuf[wave][nb][lane * 2 + 1] = dy * rstd * lw.y + lb.y;
    }
    __syncthreads();

    float acc[4];
#pragma unroll
    for (int nb = 0; nb < 4; ++nb) acc[nb] = sb1[lane];
#pragma unroll 4
    for (int c = 0; c < 128; ++c) {
        float w = sW1[c * 64 + lane];
        acc[0] += hbuf[wave][0][c] * w;
        acc[1] += hbuf[wave][1][c] * w;
        acc[2] += hbuf[wave][2][c] * w;
        acc[3] += hbuf[wave][3][c] * w;
    }
#pragma unroll
    for (int nb = 0; nb < 4; ++nb) {
        float a = fmaxf(acc[nb], 0.f);
#pragma unroll
        for (int c2 = 0; c2 < NCLS; ++c2) {
            float pv = a * sW2[lane * 3 + c2];
#pragma unroll
            for (int off = 32; off > 0; off >>= 1) pv += __shfl_xor(pv, off);
            if (lane == 0) out[(long)(nb0 + nb) * 3 + c2] = pv + sb2[c2];
        }
    }
}

extern "C" void kernel_launch(void* const* d_in, const int* in_sizes, int n_in,
                              void* d_out, int out_size, void* d_ws, size_t ws_size,
                              hipStream_t stream) {
    const float* x         = (const float*)d_in[0];
    const int*   edge_index= (const int*)d_in[1];   // harness stages integers as int32
    const float* edge_attr = (const float*)d_in[2];
    const float* Wqkv      = (const float*)d_in[3];
    const float* Wedge     = (const float*)d_in[4];
    const float* Wout      = (const float*)d_in[5];
    const float* bout      = (const float*)d_in[6];
    const float* ln_w      = (const float*)d_in[7];
    const float* ln_b      = (const float*)d_in[8];
    const float* Wc1       = (const float*)d_in[9];
    const float* bc1       = (const float*)d_in[10];
    const float* Wc2       = (const float*)d_in[11];
    const float* bc2       = (const float*)d_in[12];
    float* out = (float*)d_out;

    // workspace layout (~180 MB)
    char* ws = (char*)d_ws;
    size_t o = 0;
    auto alloc = [&](size_t bytes) -> char* {
        char* p = ws + o;
        o = (o + bytes + 255) & ~(size_t)255;
        return p;
    };
    int*       cnt       = (int*)alloc((size_t)N_NODES * 4);
    int*       row_start = (int*)alloc((size_t)(N_NODES + 1) * 4);
    int*       cursor    = (int*)alloc((size_t)N_NODES * 4);
    int*       bsum      = (int*)alloc(98 * 4);
    int*       boff      = (int*)alloc(98 * 4);
    float4*    se4       = (float4*)alloc((size_t)N_EDGES * 16);
    _Float16*  x_h       = (_Float16*)alloc((size_t)N_NODES * 128 * 2);
    _Float16*  Wqkv_t    = (_Float16*)alloc((size_t)384 * 128 * 2);
    _Float16*  Wout_t    = (_Float16*)alloc((size_t)128 * 128 * 2);
    float*     q_tab     = (float*)alloc((size_t)N_NODES * 128 * 4);
    _Float16*  kv_h      = (_Float16*)alloc((size_t)N_NODES * 256 * 2);
    _Float16*  agg_h     = (_Float16*)alloc((size_t)N_NODES * 128 * 2);
    float*     h_pre     = q_tab; // alias: q dead once k_attn completes
    (void)ws_size; (void)in_sizes; (void)n_in; (void)out_size;

    hipMemsetAsync(cnt, 0, (size_t)N_NODES * 4, stream);
    k_hist<<<N_EDGES / 256, 256, 0, stream>>>(edge_index, cnt);
    k_scan1<<<98, 256, 0, stream>>>(cnt, bsum);
    k_scan2<<<1, 128, 0, stream>>>(bsum, boff, row_start);
    k_scan3<<<98, 256, 0, stream>>>(cnt, boff, row_start, cursor);
    k_scatter<<<N_EDGES / 256, 256, 0, stream>>>(edge_index, edge_attr, cursor, se4);

    k_cvt<<<12500, 256, 0, stream>>>(x, Wqkv, Wout, x_h, Wqkv_t, Wout_t);
    k_mm_qkv<<<1563, 256, 0, stream>>>(x_h, Wqkv_t, q_tab, kv_h);
    k_attn<<<25000, 256, 0, stream>>>(q_tab, kv_h, se4, row_start, Wedge, agg_h);
    k_mm_out<<<1563, 256, 0, stream>>>(agg_h, Wout_t, bout, x, h_pre);
    k_mlp<<<6250, 256, 0, stream>>>(h_pre, ln_w, ln_b, Wc1, bc1, Wc2, bc2, out);
}